// Round 1
// baseline (1122.883 us; speedup 1.0000x reference)
//
#include <hip/hip_runtime.h>
#include <math.h>

#define MINF 1e-15f
#define ATMAX (1.0f - 1e-7f)
#define BALLMAX (1.0f - 4e-3f)

__device__ __forceinline__ float wred64(float v){
    #pragma unroll
    for (int m = 1; m < 64; m <<= 1) v += __shfl_xor(v, m, 64);
    return v;
}

// Kernel 1: segment standardize (folded) + GEMM1 (3072->128) + b1 + LayerNorm + exact GELU.
// Writes h into out[branch] region ([4][14336][128]).
__global__ __launch_bounds__(256) void k_enc1(
    const float* __restrict__ x0, const float* __restrict__ x1,
    const float* __restrict__ x2, const float* __restrict__ x3,
    const float* __restrict__ W1, const float* __restrict__ b1,
    const float* __restrict__ ln_g, const float* __restrict__ ln_b,
    float* __restrict__ hout)
{
    __shared__ float At[64][68];     // transposed A tile [k][row], pad 68 keeps 16B align, spreads banks
    __shared__ float Bt[64][128];    // W1 tile [k][col]; reused for colsum partials after K loop
    __shared__ float rowsum[64];
    __shared__ float rowsq[64];

    const int t  = threadIdx.x;
    const int br = blockIdx.y;
    const int rb = blockIdx.x;                 // 0..223
    const float* xs = (br==0)?x0:(br==1)?x1:(br==2)?x2:x3;
    const float* Wb = W1 + (size_t)br*3072*128;

    const int tx = t & 31, ty = t >> 5;        // compute mapping: rows ty*8+i, cols tx*4+j
    const int a_r = t >> 4, a_k4 = t & 15;     // A-load mapping
    const int b_c4 = t & 31;                   // B-load col group (fixed per thread)

    const size_t row0 = (size_t)rb * 64;

    float acc[8][4];
    #pragma unroll
    for (int i=0;i<8;i++){acc[i][0]=0.f;acc[i][1]=0.f;acc[i][2]=0.f;acc[i][3]=0.f;}
    float4 colacc = make_float4(0.f,0.f,0.f,0.f);
    float psum[4] = {0.f,0.f,0.f,0.f};
    float psq[4]  = {0.f,0.f,0.f,0.f};

    for (int kt = 0; kt < 48; ++kt){
        const int k0 = kt*64;
        // A: 64 rows x 64 k, 4 float4/thread; accumulate row stats while loading
        #pragma unroll
        for (int j=0;j<4;j++){
            const int r = a_r + 16*j;
            const float4 v = *(const float4*)(xs + (row0 + r)*3072 + k0 + a_k4*4);
            psum[j] += (v.x+v.y)+(v.z+v.w);
            psq[j]  += (v.x*v.x+v.y*v.y)+(v.z*v.z+v.w*v.w);
            At[a_k4*4+0][r]=v.x; At[a_k4*4+1][r]=v.y; At[a_k4*4+2][r]=v.z; At[a_k4*4+3][r]=v.w;
        }
        // B: 64 k x 128 cols, 8 float4/thread; accumulate column sums while loading
        #pragma unroll
        for (int j=0;j<8;j++){
            const int k = ty + 8*j;
            const float4 v = *(const float4*)(Wb + (size_t)(k0+k)*128 + b_c4*4);
            colacc.x+=v.x; colacc.y+=v.y; colacc.z+=v.z; colacc.w+=v.w;
            *(float4*)&Bt[k][b_c4*4] = v;
        }
        __syncthreads();
        #pragma unroll 8
        for (int k=0;k<64;k++){
            const float4 a0 = *(const float4*)&At[k][ty*8];
            const float4 a1 = *(const float4*)&At[k][ty*8+4];
            const float4 b  = *(const float4*)&Bt[k][tx*4];
            const float ar[8] = {a0.x,a0.y,a0.z,a0.w,a1.x,a1.y,a1.z,a1.w};
            #pragma unroll
            for (int i=0;i<8;i++){
                acc[i][0] = fmaf(ar[i], b.x, acc[i][0]);
                acc[i][1] = fmaf(ar[i], b.y, acc[i][1]);
                acc[i][2] = fmaf(ar[i], b.z, acc[i][2]);
                acc[i][3] = fmaf(ar[i], b.w, acc[i][3]);
            }
        }
        __syncthreads();
    }

    // row stats: 16 threads share each row (lanes [16m,16m+16) -> xor masks 1..8 stay inside)
    #pragma unroll
    for (int j=0;j<4;j++){
        float s = psum[j], q = psq[j];
        #pragma unroll
        for (int m=1;m<16;m<<=1){ s += __shfl_xor(s,m,64); q += __shfl_xor(q,m,64); }
        if ((t&15)==0){ rowsum[a_r+16*j]=s; rowsq[a_r+16*j]=q; }
    }
    // colsum partials: thread (m=ty, c4) owned the same 4 cols over all tiles
    *(float4*)&Bt[ty][b_c4*4] = colacc;
    __syncthreads();

    float colsum[4], b1v[4], gv[4], bv[4];
    {
        const float* b1p = b1  + br*128;
        const float* gp  = ln_g + br*128;
        const float* bp  = ln_b + br*128;
        #pragma unroll
        for (int j=0;j<4;j++){
            const int c = tx*4+j;
            float cs = 0.f;
            #pragma unroll
            for (int m=0;m<8;m++) cs += Bt[m][c];
            colsum[j]=cs; b1v[j]=b1p[c]; gv[j]=gp[c]; bv[j]=bp[c];
        }
    }
    #pragma unroll
    for (int i=0;i<8;i++){
        const int r = ty*8+i;
        const float rs = rowsum[r], rq = rowsq[r];
        const float mu = rs * (1.0f/3072.0f);
        float var = (rq - rs*rs*(1.0f/3072.0f)) * (1.0f/3071.0f);   // ddof=1
        var = fmaxf(var, 0.f);
        const float inv_sd = 1.0f/(sqrtf(var)+1e-6f);
        float h[4], Sh=0.f, Sq=0.f;
        #pragma unroll
        for (int j=0;j<4;j++){
            const float v = (acc[i][j] - mu*colsum[j])*inv_sd + b1v[j];
            h[j]=v; Sh+=v; Sq+=v*v;
        }
        #pragma unroll
        for (int m=1;m<32;m<<=1){ Sh += __shfl_xor(Sh,m,64); Sq += __shfl_xor(Sq,m,64); }
        const float mean = Sh*(1.0f/128.0f);
        const float v2   = fmaxf(Sq*(1.0f/128.0f) - mean*mean, 0.f);
        const float rstd = rsqrtf(v2 + 1e-5f);
        float4 o;
        float* op = &o.x;
        #pragma unroll
        for (int j=0;j<4;j++){
            const float hn = (h[j]-mean)*rstd*gv[j] + bv[j];
            op[j] = 0.5f*hn*(1.0f + erff(hn*0.70710678118654752f));   // exact GELU
        }
        *(float4*)(hout + ((size_t)br*14336 + row0 + r)*128 + tx*4) = o;
    }
}

// Kernel 2: GEMM2 (128x128) + b2 + tanh(scale)*z + expmap0 + projx, in place over h.
__global__ __launch_bounds__(256) void k_enc2(
    const float* __restrict__ W2, const float* __restrict__ b2,
    const float* __restrict__ es, float* __restrict__ z)
{
    __shared__ float Wl[128][128];
    __shared__ float ht[32][128];
    const int t = threadIdx.x;
    const size_t row0 = (size_t)blockIdx.x * 32;   // rows over [4*14336]
    const int br = (int)(row0 / 14336);
    const float* Wb = W2 + (size_t)br*128*128;

    #pragma unroll
    for (int j=0;j<16;j++){
        const int f = t + 256*j;
        const int n = f >> 5, c4 = f & 31;
        *(float4*)&Wl[n][c4*4] = *(const float4*)(Wb + n*128 + c4*4);
    }
    #pragma unroll
    for (int j=0;j<4;j++){
        const int f = t + 256*j;
        const int r = f >> 5, c4 = f & 31;
        *(float4*)&ht[r][c4*4] = *(const float4*)(z + (row0 + r)*128 + c4*4);
    }
    __syncthreads();
    const int tx = t & 31, ty = t >> 5;            // rows ty*4+i, cols tx*4+j
    float4 acc[4];
    #pragma unroll
    for (int i=0;i<4;i++) acc[i]=make_float4(0.f,0.f,0.f,0.f);
    #pragma unroll 8
    for (int n=0;n<128;n++){
        const float4 w = *(const float4*)&Wl[n][tx*4];
        #pragma unroll
        for (int i=0;i<4;i++){
            const float a = ht[ty*4+i][n];
            acc[i].x = fmaf(a,w.x,acc[i].x);
            acc[i].y = fmaf(a,w.y,acc[i].y);
            acc[i].z = fmaf(a,w.z,acc[i].z);
            acc[i].w = fmaf(a,w.w,acc[i].w);
        }
    }
    const float s = tanhf(es[0]);
    const float4 bv = *(const float4*)(b2 + br*128 + tx*4);
    #pragma unroll
    for (int i=0;i<4;i++){
        float4 u;
        u.x = s*(acc[i].x+bv.x); u.y = s*(acc[i].y+bv.y);
        u.z = s*(acc[i].z+bv.z); u.w = s*(acc[i].w+bv.w);
        float n2 = (u.x*u.x+u.y*u.y)+(u.z*u.z+u.w*u.w);
        #pragma unroll
        for (int m=1;m<32;m<<=1) n2 += __shfl_xor(n2,m,64);
        const float nn = fmaxf(sqrtf(n2), MINF);
        const float f = fminf(tanhf(nn), BALLMAX)/nn;    // expmap0 + projx fused
        u.x*=f; u.y*=f; u.z*=f; u.w*=f;
        *(float4*)(z + (row0 + ty*4+i)*128 + tx*4) = u;
    }
}

// Kernel 3: Frechet mean (10 fixed iterations) per (branch,b). One wave per task, 2 dims/lane.
// Stashes pooled[i][b] into the combined-output region at slice b, offset i*128.
__global__ __launch_bounds__(256) void k_pool(const float* __restrict__ z, float* __restrict__ out4)
{
    const int wid  = (blockIdx.x<<2) + (threadIdx.x>>6);   // 0..4095
    const int lane = threadIdx.x & 63;
    const int i = wid >> 10, b = wid & 1023;
    const float* base = z + ((size_t)i*14336 + (size_t)b*14)*128 + lane*2;
    float2 p[14]; float py2[14];
    #pragma unroll
    for (int n=0;n<14;n++){
        p[n] = *(const float2*)(base + n*128);
        py2[n] = wred64(p[n].x*p[n].x + p[n].y*p[n].y);
    }
    // init: projx(expmap0(mean(logmap0(p))))
    float gx=0.f, gy=0.f;
    #pragma unroll
    for (int n=0;n<14;n++){
        const float nn = fmaxf(sqrtf(py2[n]), MINF);
        const float f = atanhf(fminf(nn, ATMAX)) / nn;
        gx += f*p[n].x; gy += f*p[n].y;
    }
    gx *= (1.f/14.f); gy *= (1.f/14.f);
    float cx, cy;
    {
        const float g2 = wred64(gx*gx+gy*gy);
        const float ng = fmaxf(sqrtf(g2), MINF);
        const float f = fminf(tanhf(ng), BALLMAX)/ng;
        cx = f*gx; cy = f*gy;
    }
    for (int it=0; it<10; ++it){
        const float cur2 = wred64(cx*cx+cy*cy);
        const float l2i = fmaxf(1.f-cur2, MINF);           // = 2/lambda(cur)
        float sx=0.f, sy=0.f;
        #pragma unroll
        for (int n=0;n<14;n++){
            const float xy = -wred64(cx*p[n].x + cy*p[n].y);     // dot(-cur, p)
            const float k1 = 1.f + 2.f*xy + py2[n];
            const float den = fmaxf(1.f + 2.f*xy + cur2*py2[n], MINF);
            const float wx = (l2i*p[n].x - k1*cx)/den;           // note 1-cur2 == l2i here (cur2<1)
            const float wy = (l2i*p[n].y - k1*cy)/den;
            const float nw2 = wred64(wx*wx+wy*wy);
            const float nw = fmaxf(sqrtf(nw2), MINF);
            const float ff = l2i * atanhf(fminf(nw, ATMAX)) / nw;
            sx += ff*wx; sy += ff*wy;
        }
        sx *= (0.5f/14.f); sy *= (0.5f/14.f);                // u = 0.5*grad
        const float nu2 = wred64(sx*sx+sy*sy);
        const float nu = fmaxf(sqrtf(nu2), MINF);
        const float fe = tanhf(nu/l2i)/nu;                   // tanh(lambda*n/2)/n
        const float yx = fe*sx, yy = fe*sy;
        const float y2 = wred64(yx*yx+yy*yy);
        const float cyd = wred64(cx*yx+cy*yy);
        const float n1 = 1.f + 2.f*cyd + y2;
        const float n2 = 1.f - cur2;
        const float dn = fmaxf(1.f + 2.f*cyd + cur2*y2, MINF);
        float nxv = (n1*cx + n2*yx)/dn;
        float nyv = (n1*cy + n2*yy)/dn;
        const float pn2 = wred64(nxv*nxv + nyv*nyv);
        const float pn = fmaxf(sqrtf(pn2), MINF);
        if (pn > BALLMAX){ const float sc=BALLMAX/pn; nxv*=sc; nyv*=sc; }
        cx = nxv; cy = nyv;
    }
    float* st = out4 + (size_t)b*1792 + i*128 + lane*2;
    st[0]=cx; st[1]=cy;
}

// Kernel 4: softmax-weighted Mobius fusion + projx + broadcast to [B,14,128].
__global__ __launch_bounds__(256) void k_fuse(const float* __restrict__ fw, float* __restrict__ out4)
{
    const int b    = (blockIdx.x<<2) + (threadIdx.x>>6);   // 0..1023
    const int lane = threadIdx.x & 63;
    float* slice = out4 + (size_t)b*1792;
    float2 p[4];
    #pragma unroll
    for (int i=0;i<4;i++) p[i] = *(const float2*)(slice + i*128 + lane*2);
    const float f0=fw[0], f1=fw[1], f2=fw[2], f3=fw[3];
    const float mx = fmaxf(fmaxf(f0,f1), fmaxf(f2,f3));
    const float e0=expf(f0-mx), e1=expf(f1-mx), e2=expf(f2-mx), e3=expf(f3-mx);
    const float iz = 1.f/(e0+e1+e2+e3);
    const float ww[4] = {e0*iz, e1*iz, e2*iz, e3*iz};
    float cx, cy;
    {
        const float n2 = wred64(p[0].x*p[0].x + p[0].y*p[0].y);
        const float n = fmaxf(sqrtf(n2), MINF);
        const float f = tanhf(ww[0]*atanhf(fminf(n, ATMAX)))/n;
        cx = f*p[0].x; cy = f*p[0].y;
    }
    #pragma unroll
    for (int i=1;i<4;i++){
        const float n2 = wred64(p[i].x*p[i].x + p[i].y*p[i].y);
        const float n = fmaxf(sqrtf(n2), MINF);
        const float f = tanhf(ww[i]*atanhf(fminf(n, ATMAX)))/n;
        const float txv = f*p[i].x, tyv = f*p[i].y;
        const float c2 = wred64(cx*cx+cy*cy);
        const float t2 = wred64(txv*txv+tyv*tyv);
        const float ct = wred64(cx*txv+cy*tyv);
        const float n1 = 1.f+2.f*ct+t2, nk = 1.f-c2;
        const float dn = fmaxf(1.f+2.f*ct+c2*t2, MINF);
        cx = (n1*cx+nk*txv)/dn; cy = (n1*cy+nk*tyv)/dn;
    }
    {
        const float n2 = wred64(cx*cx+cy*cy);
        const float n = fmaxf(sqrtf(n2), MINF);
        if (n > BALLMAX){ const float sc=BALLMAX/n; cx*=sc; cy*=sc; }
    }
    const float2 o = make_float2(cx,cy);
    #pragma unroll
    for (int nseg=0; nseg<14; ++nseg)
        *(float2*)(slice + nseg*128 + lane*2) = o;
}

extern "C" void kernel_launch(void* const* d_in, const int* in_sizes, int n_in,
                              void* d_out, int out_size, void* d_ws, size_t ws_size,
                              hipStream_t stream)
{
    const float* x0 = (const float*)d_in[0];
    const float* x1 = (const float*)d_in[1];
    const float* x2 = (const float*)d_in[2];
    const float* x3 = (const float*)d_in[3];
    const float* W1 = (const float*)d_in[4];
    const float* b1 = (const float*)d_in[5];
    const float* lg = (const float*)d_in[6];
    const float* lb = (const float*)d_in[7];
    const float* W2 = (const float*)d_in[8];
    const float* b2 = (const float*)d_in[9];
    const float* es = (const float*)d_in[10];
    const float* fw = (const float*)d_in[11];
    float* out  = (float*)d_out;
    float* out4 = out + (size_t)4*14336*128;   // combined-output region (also pooled stash)

    dim3 g1(224, 4);
    k_enc1<<<g1, 256, 0, stream>>>(x0,x1,x2,x3,W1,b1,lg,lb,out);
    k_enc2<<<1792, 256, 0, stream>>>(W2,b2,es,out);
    k_pool<<<1024, 256, 0, stream>>>(out,out4);
    k_fuse<<<256, 256, 0, stream>>>(fw,out4);
}

// Round 2
// 500.696 us; speedup vs baseline: 2.2426x; 2.2426x over previous
//
#include <hip/hip_runtime.h>
#include <math.h>

#define MINF 1e-15f
#define ATMAX (1.0f - 1e-7f)
#define BALLMAX (1.0f - 4e-3f)

typedef __attribute__((ext_vector_type(8))) short bf16x8;
typedef __attribute__((ext_vector_type(4))) float f32x4;

__device__ __forceinline__ float wred64(float v){
    #pragma unroll
    for (int m = 1; m < 64; m <<= 1) v += __shfl_xor(v, m, 64);
    return v;
}

// pack two fp32 -> two bf16 (RNE), low = a, high = b
__device__ __forceinline__ unsigned pkbf(float a, float b){
    unsigned ua = __float_as_uint(a); ua += 0x7FFFu + ((ua>>16)&1u);
    unsigned ub = __float_as_uint(b); ub += 0x7FFFu + ((ub>>16)&1u);
    return (ua>>16) | (ub & 0xFFFF0000u);
}

// Prep: build pre-swizzled bf16 LDS images of W1 per (branch, K-tile) into ws,
// plus per-column partial sums of W1 (8 octs per branch) for the folded standardize.
// grid (56,4): x<48 -> image tile kt=x ; x>=48 -> colsum oct = x-48.
__global__ __launch_bounds__(256) void k_prep(const float* __restrict__ W1, float* __restrict__ ws)
{
    const int br = blockIdx.y;
    const int bx = blockIdx.x;
    const int t  = threadIdx.x;
    if (bx < 48){
        __shared__ unsigned short img[8192];           // 16 KB swizzled [col][k] bf16 image
        const int kt = bx;
        const float* src = W1 + (size_t)br*393216 + (size_t)kt*64*128;
        char* ic = (char*)img;
        #pragma unroll
        for (int j=0;j<8;j++){
            const int k  = (t>>5) + 8*j;
            const int c0 = (t&31)*4;
            const float4 v = *(const float4*)(src + k*128 + c0);
            const float vv[4] = {v.x,v.y,v.z,v.w};
            #pragma unroll
            for (int e=0;e<4;e++){
                const int col = c0 + e;
                const int off = (col*128 + k*2) ^ ((col&7)<<4);   // XOR swizzle (T2)
                unsigned u = __float_as_uint(vv[e]); u += 0x7FFFu + ((u>>16)&1u);
                *(unsigned short*)(ic + off) = (unsigned short)(u>>16);
            }
        }
        __syncthreads();
        float4* dst = (float4*)((char*)ws + ((size_t)(br*48+kt)<<14));
        const float4* s4 = (const float4*)ic;
        #pragma unroll
        for (int j=0;j<4;j++) dst[t + 256*j] = s4[t + 256*j];
    } else {
        const int oct = bx - 48;
        const int col = t & 127;
        const int par = t >> 7;
        const float* src = W1 + (size_t)br*393216 + (size_t)(oct*384 + par)*128 + col;
        float s = 0.f;
        for (int i=0;i<192;i++) s += src[i*256];
        __shared__ float red[256];
        red[t] = s;
        __syncthreads();
        if (t < 128) ws[786432 + (br*8+oct)*128 + t] = red[t] + red[t+128];
    }
}

// Kernel 1: bf16 MFMA GEMM1 (3072->128) with folded segment-standardize + b1 + LN + exact GELU.
// 128x128 tile, BK=64, 4 waves; wave w owns rows w*32..w*32+31 x all 128 cols (LN wave-local).
__global__ __launch_bounds__(256) void k_enc1(
    const float* __restrict__ x0, const float* __restrict__ x1,
    const float* __restrict__ x2, const float* __restrict__ x3,
    const float* __restrict__ ws, const float* __restrict__ b1,
    const float* __restrict__ ln_g, const float* __restrict__ ln_b,
    float* __restrict__ hout)
{
    __shared__ unsigned short As[8192];   // swizzled [row][k] bf16, 16 KB
    __shared__ unsigned short Bs[8192];   // swizzled [col][k] bf16, 16 KB (linear copy of ws image)
    __shared__ float smu[128], sisd[128];

    const int t  = threadIdx.x;
    const int br = blockIdx.y;
    const size_t row0 = (size_t)blockIdx.x * 128;
    const float* xs = (br==0)?x0:(br==1)?x1:(br==2)?x2:x3;
    const char* bimg = (const char*)ws + ((size_t)(br*48)<<14);

    const int ar = t>>4, kq = t&15;           // A-staging: rows ar+16j, float4 at k=kq*4
    const int lane = t & 63, w = t >> 6;
    const int l15 = lane & 15, hi = lane >> 4;

    float psum[8], psq[8];
    #pragma unroll
    for (int j=0;j<8;j++){ psum[j]=0.f; psq[j]=0.f; }
    f32x4 acc[2][8];
    #pragma unroll
    for (int m=0;m<2;m++)
        #pragma unroll
        for (int n=0;n<8;n++) acc[m][n] = (f32x4){0.f,0.f,0.f,0.f};

    const float* asrc = xs + (row0 + ar)*3072 + kq*4;
    char* Ac = (char*)As;
    char* Bc = (char*)Bs;
    const unsigned swzA = (unsigned)((ar&7)<<4);
    const unsigned swzR = (unsigned)((l15&7)<<4);

    for (int kt=0; kt<48; ++kt){
        // B stage: linear 16 KB copy (image is pre-swizzled)
        {
            const float4* bsrc = (const float4*)(bimg + ((size_t)kt<<14));
            float4* bdst = (float4*)Bs;
            #pragma unroll
            for (int j=0;j<4;j++) bdst[t + 256*j] = bsrc[t + 256*j];
        }
        // A stage: fp32 load (coalesced) -> stats -> bf16 pack -> swizzled ds_write
        #pragma unroll
        for (int j=0;j<8;j++){
            const float4 v = *(const float4*)(asrc + j*16*3072 + kt*64);
            psum[j] += (v.x+v.y)+(v.z+v.w);
            psq[j]  += (v.x*v.x+v.y*v.y)+(v.z*v.z+v.w*v.w);
            uint2 p; p.x = pkbf(v.x, v.y); p.y = pkbf(v.z, v.w);
            const int row = ar + 16*j;
            *(uint2*)(Ac + (((unsigned)(row*128 + kq*8)) ^ swzA)) = p;
        }
        __syncthreads();
        #pragma unroll
        for (int ks=0; ks<2; ++ks){
            const unsigned rb = (unsigned)((w*32 + l15)*128 + ks*64 + hi*16);
            bf16x8 a0 = *(const bf16x8*)(Ac + ((rb          ) ^ swzR));
            bf16x8 a1 = *(const bf16x8*)(Ac + ((rb + 16*128 ) ^ swzR));
            #pragma unroll
            for (int n=0;n<8;n++){
                const unsigned cb = (unsigned)((n*16 + l15)*128 + ks*64 + hi*16);
                bf16x8 b = *(const bf16x8*)(Bc + (cb ^ swzR));   // (col&7)==(l15&7)
                acc[0][n] = __builtin_amdgcn_mfma_f32_16x16x32_bf16(a0, b, acc[0][n], 0,0,0);
                acc[1][n] = __builtin_amdgcn_mfma_f32_16x16x32_bf16(a1, b, acc[1][n], 0,0,0);
            }
        }
        __syncthreads();
    }

    // row stats: 16 threads (same ar, kq=0..15) share each row; shfl masks stay in-group
    #pragma unroll
    for (int j=0;j<8;j++){
        float s = psum[j], q = psq[j];
        #pragma unroll
        for (int m=1;m<16;m<<=1){ s += __shfl_xor(s,m,64); q += __shfl_xor(q,m,64); }
        if (kq==0){
            const int row = ar + 16*j;
            const float mu = s*(1.0f/3072.0f);
            float var = (q - s*s*(1.0f/3072.0f))*(1.0f/3071.0f);  // ddof=1
            var = fmaxf(var, 0.f);
            smu[row]  = mu;
            sisd[row] = 1.0f/(sqrtf(var)+1e-6f);
        }
    }
    __syncthreads();

    // per-column constants
    float cs[8], b1v[8], gv[8], bev[8];
    {
        const float* csb = ws + 786432 + br*1024;
        #pragma unroll
        for (int n=0;n<8;n++){
            const int c = n*16 + l15;
            float s = 0.f;
            #pragma unroll
            for (int o=0;o<8;o++) s += csb[o*128 + c];
            cs[n]  = s;
            b1v[n] = b1[br*128+c]; gv[n] = ln_g[br*128+c]; bev[n] = ln_b[br*128+c];
        }
    }

    // epilogue: standardize-fold + b1 + LN(128) + exact GELU, store fp32 h
    #pragma unroll
    for (int m=0;m<2;m++){
        #pragma unroll
        for (int q=0;q<4;q++){
            const int row = w*32 + m*16 + hi*4 + q;
            const float mu = smu[row], isd = sisd[row];
            float h[8], Sh=0.f, Sq=0.f;
            #pragma unroll
            for (int n=0;n<8;n++){
                const float v = (acc[m][n][q] - mu*cs[n])*isd + b1v[n];
                h[n]=v; Sh+=v; Sq+=v*v;
            }
            #pragma unroll
            for (int mm=1;mm<16;mm<<=1){ Sh += __shfl_xor(Sh,mm,64); Sq += __shfl_xor(Sq,mm,64); }
            const float mean = Sh*(1.0f/128.0f);
            const float vv   = fmaxf(Sq*(1.0f/128.0f) - mean*mean, 0.f);
            const float rstd = rsqrtf(vv + 1e-5f);
            float* orow = hout + ((size_t)br*14336 + row0 + row)*128;
            #pragma unroll
            for (int n=0;n<8;n++){
                const float hn = (h[n]-mean)*rstd*gv[n] + bev[n];
                orow[n*16+l15] = 0.5f*hn*(1.0f + erff(hn*0.70710678118654752f));
            }
        }
    }
}

// Kernel 2: GEMM2 (128x128) + b2 + tanh(scale)*z + expmap0 + projx, in place over h.
__global__ __launch_bounds__(256) void k_enc2(
    const float* __restrict__ W2, const float* __restrict__ b2,
    const float* __restrict__ es, float* __restrict__ z)
{
    __shared__ float Wl[128][128];
    __shared__ float ht[32][128];
    const int t = threadIdx.x;
    const size_t row0 = (size_t)blockIdx.x * 32;
    const int br = (int)(row0 / 14336);
    const float* Wb = W2 + (size_t)br*128*128;

    #pragma unroll
    for (int j=0;j<16;j++){
        const int f = t + 256*j;
        const int n = f >> 5, c4 = f & 31;
        *(float4*)&Wl[n][c4*4] = *(const float4*)(Wb + n*128 + c4*4);
    }
    #pragma unroll
    for (int j=0;j<4;j++){
        const int f = t + 256*j;
        const int r = f >> 5, c4 = f & 31;
        *(float4*)&ht[r][c4*4] = *(const float4*)(z + (row0 + r)*128 + c4*4);
    }
    __syncthreads();
    const int tx = t & 31, ty = t >> 5;
    float4 acc[4];
    #pragma unroll
    for (int i=0;i<4;i++) acc[i]=make_float4(0.f,0.f,0.f,0.f);
    #pragma unroll 8
    for (int n=0;n<128;n++){
        const float4 w = *(const float4*)&Wl[n][tx*4];
        #pragma unroll
        for (int i=0;i<4;i++){
            const float a = ht[ty*4+i][n];
            acc[i].x = fmaf(a,w.x,acc[i].x);
            acc[i].y = fmaf(a,w.y,acc[i].y);
            acc[i].z = fmaf(a,w.z,acc[i].z);
            acc[i].w = fmaf(a,w.w,acc[i].w);
        }
    }
    const float s = tanhf(es[0]);
    const float4 bv = *(const float4*)(b2 + br*128 + tx*4);
    #pragma unroll
    for (int i=0;i<4;i++){
        float4 u;
        u.x = s*(acc[i].x+bv.x); u.y = s*(acc[i].y+bv.y);
        u.z = s*(acc[i].z+bv.z); u.w = s*(acc[i].w+bv.w);
        float n2 = (u.x*u.x+u.y*u.y)+(u.z*u.z+u.w*u.w);
        #pragma unroll
        for (int m=1;m<32;m<<=1) n2 += __shfl_xor(n2,m,64);
        const float nn = fmaxf(sqrtf(n2), MINF);
        const float f = fminf(tanhf(nn), BALLMAX)/nn;
        u.x*=f; u.y*=f; u.z*=f; u.w*=f;
        *(float4*)(z + (row0 + ty*4+i)*128 + tx*4) = u;
    }
}

// Kernel 3: Frechet mean (10 fixed iterations). One wave per (branch,b), 2 dims/lane.
__global__ __launch_bounds__(256) void k_pool(const float* __restrict__ z, float* __restrict__ out4)
{
    const int wid  = (blockIdx.x<<2) + (threadIdx.x>>6);
    const int lane = threadIdx.x & 63;
    const int i = wid >> 10, b = wid & 1023;
    const float* base = z + ((size_t)i*14336 + (size_t)b*14)*128 + lane*2;
    float2 p[14]; float py2[14];
    #pragma unroll
    for (int n=0;n<14;n++){
        p[n] = *(const float2*)(base + n*128);
        py2[n] = wred64(p[n].x*p[n].x + p[n].y*p[n].y);
    }
    float gx=0.f, gy=0.f;
    #pragma unroll
    for (int n=0;n<14;n++){
        const float nn = fmaxf(sqrtf(py2[n]), MINF);
        const float f = atanhf(fminf(nn, ATMAX)) / nn;
        gx += f*p[n].x; gy += f*p[n].y;
    }
    gx *= (1.f/14.f); gy *= (1.f/14.f);
    float cx, cy;
    {
        const float g2 = wred64(gx*gx+gy*gy);
        const float ng = fmaxf(sqrtf(g2), MINF);
        const float f = fminf(tanhf(ng), BALLMAX)/ng;
        cx = f*gx; cy = f*gy;
    }
    for (int it=0; it<10; ++it){
        const float cur2 = wred64(cx*cx+cy*cy);
        const float l2i = fmaxf(1.f-cur2, MINF);
        float sx=0.f, sy=0.f;
        #pragma unroll
        for (int n=0;n<14;n++){
            const float xy = -wred64(cx*p[n].x + cy*p[n].y);
            const float k1 = 1.f + 2.f*xy + py2[n];
            const float den = fmaxf(1.f + 2.f*xy + cur2*py2[n], MINF);
            const float wx = (l2i*p[n].x - k1*cx)/den;
            const float wy = (l2i*p[n].y - k1*cy)/den;
            const float nw2 = wred64(wx*wx+wy*wy);
            const float nw = fmaxf(sqrtf(nw2), MINF);
            const float ff = l2i * atanhf(fminf(nw, ATMAX)) / nw;
            sx += ff*wx; sy += ff*wy;
        }
        sx *= (0.5f/14.f); sy *= (0.5f/14.f);
        const float nu2 = wred64(sx*sx+sy*sy);
        const float nu = fmaxf(sqrtf(nu2), MINF);
        const float fe = tanhf(nu/l2i)/nu;
        const float yx = fe*sx, yy = fe*sy;
        const float y2 = wred64(yx*yx+yy*yy);
        const float cyd = wred64(cx*yx+cy*yy);
        const float n1 = 1.f + 2.f*cyd + y2;
        const float n2 = 1.f - cur2;
        const float dn = fmaxf(1.f + 2.f*cyd + cur2*y2, MINF);
        float nxv = (n1*cx + n2*yx)/dn;
        float nyv = (n1*cy + n2*yy)/dn;
        const float pn2 = wred64(nxv*nxv + nyv*nyv);
        const float pn = fmaxf(sqrtf(pn2), MINF);
        if (pn > BALLMAX){ const float sc=BALLMAX/pn; nxv*=sc; nyv*=sc; }
        cx = nxv; cy = nyv;
    }
    float* st = out4 + (size_t)b*1792 + i*128 + lane*2;
    st[0]=cx; st[1]=cy;
}

// Kernel 4: softmax-weighted Mobius fusion + projx + broadcast to [B,14,128].
__global__ __launch_bounds__(256) void k_fuse(const float* __restrict__ fw, float* __restrict__ out4)
{
    const int b    = (blockIdx.x<<2) + (threadIdx.x>>6);
    const int lane = threadIdx.x & 63;
    float* slice = out4 + (size_t)b*1792;
    float2 p[4];
    #pragma unroll
    for (int i=0;i<4;i++) p[i] = *(const float2*)(slice + i*128 + lane*2);
    const float f0=fw[0], f1=fw[1], f2=fw[2], f3=fw[3];
    const float mx = fmaxf(fmaxf(f0,f1), fmaxf(f2,f3));
    const float e0=expf(f0-mx), e1=expf(f1-mx), e2=expf(f2-mx), e3=expf(f3-mx);
    const float iz = 1.f/(e0+e1+e2+e3);
    const float ww[4] = {e0*iz, e1*iz, e2*iz, e3*iz};
    float cx, cy;
    {
        const float n2 = wred64(p[0].x*p[0].x + p[0].y*p[0].y);
        const float n = fmaxf(sqrtf(n2), MINF);
        const float f = tanhf(ww[0]*atanhf(fminf(n, ATMAX)))/n;
        cx = f*p[0].x; cy = f*p[0].y;
    }
    #pragma unroll
    for (int i=1;i<4;i++){
        const float n2 = wred64(p[i].x*p[i].x + p[i].y*p[i].y);
        const float n = fmaxf(sqrtf(n2), MINF);
        const float f = tanhf(ww[i]*atanhf(fminf(n, ATMAX)))/n;
        const float txv = f*p[i].x, tyv = f*p[i].y;
        const float c2 = wred64(cx*cx+cy*cy);
        const float t2 = wred64(txv*txv+tyv*tyv);
        const float ct = wred64(cx*txv+cy*tyv);
        const float n1 = 1.f+2.f*ct+t2, nk = 1.f-c2;
        const float dn = fmaxf(1.f+2.f*ct+c2*t2, MINF);
        cx = (n1*cx+nk*txv)/dn; cy = (n1*cy+nk*tyv)/dn;
    }
    {
        const float n2 = wred64(cx*cx+cy*cy);
        const float n = fmaxf(sqrtf(n2), MINF);
        if (n > BALLMAX){ const float sc=BALLMAX/n; cx*=sc; cy*=sc; }
    }
    const float2 o = make_float2(cx,cy);
    #pragma unroll
    for (int nseg=0; nseg<14; ++nseg)
        *(float2*)(slice + nseg*128 + lane*2) = o;
}

extern "C" void kernel_launch(void* const* d_in, const int* in_sizes, int n_in,
                              void* d_out, int out_size, void* d_ws, size_t ws_size,
                              hipStream_t stream)
{
    const float* x0 = (const float*)d_in[0];
    const float* x1 = (const float*)d_in[1];
    const float* x2 = (const float*)d_in[2];
    const float* x3 = (const float*)d_in[3];
    const float* W1 = (const float*)d_in[4];
    const float* b1 = (const float*)d_in[5];
    const float* lg = (const float*)d_in[6];
    const float* lb = (const float*)d_in[7];
    const float* W2 = (const float*)d_in[8];
    const float* b2 = (const float*)d_in[9];
    const float* es = (const float*)d_in[10];
    const float* fw = (const float*)d_in[11];
    float* out  = (float*)d_out;
    float* out4 = out + (size_t)4*14336*128;
    float* ws   = (float*)d_ws;     // 3 MB W1 images + 16 KB colsum partials

    dim3 gp(56, 4);
    k_prep<<<gp, 256, 0, stream>>>(W1, ws);
    dim3 g1(112, 4);
    k_enc1<<<g1, 256, 0, stream>>>(x0,x1,x2,x3,ws,b1,lg,lb,out);
    k_enc2<<<1792, 256, 0, stream>>>(W2,b2,es,out);
    k_pool<<<1024, 256, 0, stream>>>(out,out4);
    k_fuse<<<256, 256, 0, stream>>>(fw,out4);
}

// Round 3
// 292.679 us; speedup vs baseline: 3.8366x; 1.7107x over previous
//
#include <hip/hip_runtime.h>
#include <math.h>

#define MINF 1e-15f
#define ATMAX (1.0f - 1e-7f)
#define BALLMAX (1.0f - 4e-3f)

typedef __attribute__((ext_vector_type(8))) short bf16x8;
typedef __attribute__((ext_vector_type(4))) float f32x4;

__device__ __forceinline__ float wred64(float v){
    #pragma unroll
    for (int m = 1; m < 64; m <<= 1) v += __shfl_xor(v, m, 64);
    return v;
}
__device__ __forceinline__ float red16(float v){
    #pragma unroll
    for (int m = 1; m < 16; m <<= 1) v += __shfl_xor(v, m, 64);
    return v;
}
// fast atanh for x in [0, 1): 0.5*ln((1+x)/(1-x))
__device__ __forceinline__ float fatanh(float x){
    return 0.34657359028f * __log2f(__fdividef(1.f + x, 1.f - x));
}
// fast tanh for x >= 0
__device__ __forceinline__ float ftanh(float x){
    const float e = __expf(-2.f * x);
    return __fdividef(1.f - e, 1.f + e);
}

// pack two fp32 -> two bf16 (RNE), low = a, high = b
__device__ __forceinline__ unsigned pkbf(float a, float b){
    unsigned ua = __float_as_uint(a); ua += 0x7FFFu + ((ua>>16)&1u);
    unsigned ub = __float_as_uint(b); ub += 0x7FFFu + ((ub>>16)&1u);
    return (ua>>16) | (ub & 0xFFFF0000u);
}

// Prep: build pre-swizzled bf16 LDS images of W1 per (branch, K-tile) into ws,
// plus per-column partial sums of W1 (8 octs per branch) for the folded standardize.
__global__ __launch_bounds__(256) void k_prep(const float* __restrict__ W1, float* __restrict__ ws)
{
    const int br = blockIdx.y;
    const int bx = blockIdx.x;
    const int t  = threadIdx.x;
    if (bx < 48){
        __shared__ unsigned short img[8192];           // 16 KB swizzled [col][k] bf16 image
        const int kt = bx;
        const float* src = W1 + (size_t)br*393216 + (size_t)kt*64*128;
        char* ic = (char*)img;
        #pragma unroll
        for (int j=0;j<8;j++){
            const int k  = (t>>5) + 8*j;
            const int c0 = (t&31)*4;
            const float4 v = *(const float4*)(src + k*128 + c0);
            const float vv[4] = {v.x,v.y,v.z,v.w};
            #pragma unroll
            for (int e=0;e<4;e++){
                const int col = c0 + e;
                const int off = (col*128 + k*2) ^ ((col&7)<<4);   // XOR swizzle (T2)
                unsigned u = __float_as_uint(vv[e]); u += 0x7FFFu + ((u>>16)&1u);
                *(unsigned short*)(ic + off) = (unsigned short)(u>>16);
            }
        }
        __syncthreads();
        float4* dst = (float4*)((char*)ws + ((size_t)(br*48+kt)<<14));
        const float4* s4 = (const float4*)ic;
        #pragma unroll
        for (int j=0;j<4;j++) dst[t + 256*j] = s4[t + 256*j];
    } else {
        const int oct = bx - 48;
        const int col = t & 127;
        const int par = t >> 7;
        const float* src = W1 + (size_t)br*393216 + (size_t)(oct*384 + par)*128 + col;
        float s = 0.f;
        for (int i=0;i<192;i++) s += src[i*256];
        __shared__ float red[256];
        red[t] = s;
        __syncthreads();
        if (t < 128) ws[786432 + (br*8+oct)*128 + t] = red[t] + red[t+128];
    }
}

// Kernel 1: bf16 MFMA GEMM1 (3072->128) with folded segment-standardize + b1 + LN + exact GELU.
__global__ __launch_bounds__(256) void k_enc1(
    const float* __restrict__ x0, const float* __restrict__ x1,
    const float* __restrict__ x2, const float* __restrict__ x3,
    const float* __restrict__ ws, const float* __restrict__ b1,
    const float* __restrict__ ln_g, const float* __restrict__ ln_b,
    float* __restrict__ hout)
{
    __shared__ unsigned short As[8192];   // swizzled [row][k] bf16, 16 KB
    __shared__ unsigned short Bs[8192];   // swizzled [col][k] bf16, 16 KB
    __shared__ float smu[128], sisd[128];

    const int t  = threadIdx.x;
    const int br = blockIdx.y;
    const size_t row0 = (size_t)blockIdx.x * 128;
    const float* xs = (br==0)?x0:(br==1)?x1:(br==2)?x2:x3;
    const char* bimg = (const char*)ws + ((size_t)(br*48)<<14);

    const int ar = t>>4, kq = t&15;
    const int lane = t & 63, w = t >> 6;
    const int l15 = lane & 15, hi = lane >> 4;

    float psum[8], psq[8];
    #pragma unroll
    for (int j=0;j<8;j++){ psum[j]=0.f; psq[j]=0.f; }
    f32x4 acc[2][8];
    #pragma unroll
    for (int m=0;m<2;m++)
        #pragma unroll
        for (int n=0;n<8;n++) acc[m][n] = (f32x4){0.f,0.f,0.f,0.f};

    const float* asrc = xs + (row0 + ar)*3072 + kq*4;
    char* Ac = (char*)As;
    char* Bc = (char*)Bs;
    const unsigned swzA = (unsigned)((ar&7)<<4);
    const unsigned swzR = (unsigned)((l15&7)<<4);

    for (int kt=0; kt<48; ++kt){
        {
            const float4* bsrc = (const float4*)(bimg + ((size_t)kt<<14));
            float4* bdst = (float4*)Bs;
            #pragma unroll
            for (int j=0;j<4;j++) bdst[t + 256*j] = bsrc[t + 256*j];
        }
        #pragma unroll
        for (int j=0;j<8;j++){
            const float4 v = *(const float4*)(asrc + j*16*3072 + kt*64);
            psum[j] += (v.x+v.y)+(v.z+v.w);
            psq[j]  += (v.x*v.x+v.y*v.y)+(v.z*v.z+v.w*v.w);
            uint2 p; p.x = pkbf(v.x, v.y); p.y = pkbf(v.z, v.w);
            const int row = ar + 16*j;
            *(uint2*)(Ac + (((unsigned)(row*128 + kq*8)) ^ swzA)) = p;
        }
        __syncthreads();
        #pragma unroll
        for (int ks=0; ks<2; ++ks){
            const unsigned rb = (unsigned)((w*32 + l15)*128 + ks*64 + hi*16);
            bf16x8 a0 = *(const bf16x8*)(Ac + ((rb          ) ^ swzR));
            bf16x8 a1 = *(const bf16x8*)(Ac + ((rb + 16*128 ) ^ swzR));
            #pragma unroll
            for (int n=0;n<8;n++){
                const unsigned cb = (unsigned)((n*16 + l15)*128 + ks*64 + hi*16);
                bf16x8 b = *(const bf16x8*)(Bc + (cb ^ swzR));
                acc[0][n] = __builtin_amdgcn_mfma_f32_16x16x32_bf16(a0, b, acc[0][n], 0,0,0);
                acc[1][n] = __builtin_amdgcn_mfma_f32_16x16x32_bf16(a1, b, acc[1][n], 0,0,0);
            }
        }
        __syncthreads();
    }

    #pragma unroll
    for (int j=0;j<8;j++){
        float s = psum[j], q = psq[j];
        #pragma unroll
        for (int m=1;m<16;m<<=1){ s += __shfl_xor(s,m,64); q += __shfl_xor(q,m,64); }
        if (kq==0){
            const int row = ar + 16*j;
            const float mu = s*(1.0f/3072.0f);
            float var = (q - s*s*(1.0f/3072.0f))*(1.0f/3071.0f);
            var = fmaxf(var, 0.f);
            smu[row]  = mu;
            sisd[row] = 1.0f/(sqrtf(var)+1e-6f);
        }
    }
    __syncthreads();

    float cs[8], b1v[8], gv[8], bev[8];
    {
        const float* csb = ws + 786432 + br*1024;
        #pragma unroll
        for (int n=0;n<8;n++){
            const int c = n*16 + l15;
            float s = 0.f;
            #pragma unroll
            for (int o=0;o<8;o++) s += csb[o*128 + c];
            cs[n]  = s;
            b1v[n] = b1[br*128+c]; gv[n] = ln_g[br*128+c]; bev[n] = ln_b[br*128+c];
        }
    }

    #pragma unroll
    for (int m=0;m<2;m++){
        #pragma unroll
        for (int q=0;q<4;q++){
            const int row = w*32 + m*16 + hi*4 + q;
            const float mu = smu[row], isd = sisd[row];
            float h[8], Sh=0.f, Sq=0.f;
            #pragma unroll
            for (int n=0;n<8;n++){
                const float v = (acc[m][n][q] - mu*cs[n])*isd + b1v[n];
                h[n]=v; Sh+=v; Sq+=v*v;
            }
            #pragma unroll
            for (int mm=1;mm<16;mm<<=1){ Sh += __shfl_xor(Sh,mm,64); Sq += __shfl_xor(Sq,mm,64); }
            const float mean = Sh*(1.0f/128.0f);
            const float vv   = fmaxf(Sq*(1.0f/128.0f) - mean*mean, 0.f);
            const float rstd = rsqrtf(vv + 1e-5f);
            float* orow = hout + ((size_t)br*14336 + row0 + row)*128;
            #pragma unroll
            for (int n=0;n<8;n++){
                const float hn = (h[n]-mean)*rstd*gv[n] + bev[n];
                orow[n*16+l15] = 0.5f*hn*(1.0f + erff(hn*0.70710678118654752f));
            }
        }
    }
}

// Kernel 2: GEMM2 (128x128) + b2 + tanh(scale)*z + expmap0 + projx, in place over h.
__global__ __launch_bounds__(256) void k_enc2(
    const float* __restrict__ W2, const float* __restrict__ b2,
    const float* __restrict__ es, float* __restrict__ z)
{
    __shared__ float Wl[128][128];
    __shared__ float ht[32][128];
    const int t = threadIdx.x;
    const size_t row0 = (size_t)blockIdx.x * 32;
    const int br = (int)(row0 / 14336);
    const float* Wb = W2 + (size_t)br*128*128;

    #pragma unroll
    for (int j=0;j<16;j++){
        const int f = t + 256*j;
        const int n = f >> 5, c4 = f & 31;
        *(float4*)&Wl[n][c4*4] = *(const float4*)(Wb + n*128 + c4*4);
    }
    #pragma unroll
    for (int j=0;j<4;j++){
        const int f = t + 256*j;
        const int r = f >> 5, c4 = f & 31;
        *(float4*)&ht[r][c4*4] = *(const float4*)(z + (row0 + r)*128 + c4*4);
    }
    __syncthreads();
    const int tx = t & 31, ty = t >> 5;
    float4 acc[4];
    #pragma unroll
    for (int i=0;i<4;i++) acc[i]=make_float4(0.f,0.f,0.f,0.f);
    #pragma unroll 8
    for (int n=0;n<128;n++){
        const float4 w = *(const float4*)&Wl[n][tx*4];
        #pragma unroll
        for (int i=0;i<4;i++){
            const float a = ht[ty*4+i][n];
            acc[i].x = fmaf(a,w.x,acc[i].x);
            acc[i].y = fmaf(a,w.y,acc[i].y);
            acc[i].z = fmaf(a,w.z,acc[i].z);
            acc[i].w = fmaf(a,w.w,acc[i].w);
        }
    }
    const float s = tanhf(es[0]);
    const float4 bv = *(const float4*)(b2 + br*128 + tx*4);
    #pragma unroll
    for (int i=0;i<4;i++){
        float4 u;
        u.x = s*(acc[i].x+bv.x); u.y = s*(acc[i].y+bv.y);
        u.z = s*(acc[i].z+bv.z); u.w = s*(acc[i].w+bv.w);
        float n2 = (u.x*u.x+u.y*u.y)+(u.z*u.z+u.w*u.w);
        #pragma unroll
        for (int m=1;m<32;m<<=1) n2 += __shfl_xor(n2,m,64);
        const float nn = fmaxf(sqrtf(n2), MINF);
        const float f = fminf(tanhf(nn), BALLMAX)/nn;
        u.x*=f; u.y*=f; u.z*=f; u.w*=f;
        *(float4*)(z + (row0 + ty*4+i)*128 + tx*4) = u;
    }
}

// Kernel 3: Frechet mean, 10 fixed iterations. 16 lanes/task, 8 dims/lane, 4 tasks/wave.
__global__ __launch_bounds__(256) void k_pool(const float* __restrict__ z, float* __restrict__ out4)
{
    const int t = threadIdx.x;
    const int task = (blockIdx.x<<4) + (t>>4);     // 0..4095
    const int s = t & 15;
    const int i = task >> 10, b = task & 1023;
    const float* base = z + ((size_t)i*14336 + (size_t)b*14)*128 + s*8;

    float p[14][8]; float py2[14];
    #pragma unroll
    for (int n=0;n<14;n++){
        const float4 v0 = *(const float4*)(base + n*128);
        const float4 v1 = *(const float4*)(base + n*128 + 4);
        p[n][0]=v0.x; p[n][1]=v0.y; p[n][2]=v0.z; p[n][3]=v0.w;
        p[n][4]=v1.x; p[n][5]=v1.y; p[n][6]=v1.z; p[n][7]=v1.w;
        float q=0.f;
        #pragma unroll
        for (int d=0;d<8;d++) q = fmaf(p[n][d],p[n][d],q);
        py2[n] = red16(q);
    }
    float c[8];
    {
        float g[8];
        #pragma unroll
        for (int d=0;d<8;d++) g[d]=0.f;
        #pragma unroll
        for (int n=0;n<14;n++){
            const float nn = fmaxf(sqrtf(py2[n]), MINF);
            const float f = __fdividef(fatanh(fminf(nn, ATMAX)), nn);
            #pragma unroll
            for (int d=0;d<8;d++) g[d] = fmaf(f, p[n][d], g[d]);
        }
        float g2=0.f;
        #pragma unroll
        for (int d=0;d<8;d++){ g[d] *= (1.f/14.f); g2 = fmaf(g[d],g[d],g2); }
        g2 = red16(g2);
        const float ng = fmaxf(sqrtf(g2), MINF);
        const float f = __fdividef(fminf(ftanh(ng), BALLMAX), ng);
        #pragma unroll
        for (int d=0;d<8;d++) c[d] = f*g[d];
    }
    for (int it=0; it<10; ++it){
        float c2p=0.f;
        #pragma unroll
        for (int d=0;d<8;d++) c2p = fmaf(c[d],c[d],c2p);
        const float cur2 = red16(c2p);
        const float l2i = fmaxf(1.f-cur2, MINF);
        float sacc[8];
        #pragma unroll
        for (int d=0;d<8;d++) sacc[d]=0.f;
        #pragma unroll
        for (int n=0;n<14;n++){
            float dp=0.f;
            #pragma unroll
            for (int d=0;d<8;d++) dp = fmaf(c[d],p[n][d],dp);
            const float xy = -red16(dp);
            const float k1 = 1.f + 2.f*xy + py2[n];
            const float rden = __fdividef(1.f, fmaxf(1.f + 2.f*xy + cur2*py2[n], MINF));
            float w[8], nw2p=0.f;
            #pragma unroll
            for (int d=0;d<8;d++){
                w[d] = (l2i*p[n][d] - k1*c[d])*rden;
                nw2p = fmaf(w[d],w[d],nw2p);
            }
            const float nw2 = red16(nw2p);
            const float nw = fmaxf(sqrtf(nw2), MINF);
            const float ff = l2i * __fdividef(fatanh(fminf(nw, ATMAX)), nw);
            #pragma unroll
            for (int d=0;d<8;d++) sacc[d] = fmaf(ff, w[d], sacc[d]);
        }
        float nu2p=0.f;
        #pragma unroll
        for (int d=0;d<8;d++){ sacc[d] *= (0.5f/14.f); nu2p = fmaf(sacc[d],sacc[d],nu2p); }
        const float nu2 = red16(nu2p);
        const float nu = fmaxf(sqrtf(nu2), MINF);
        const float fe = __fdividef(ftanh(__fdividef(nu, l2i)), nu);
        float y[8], y2p=0.f, cydp=0.f;
        #pragma unroll
        for (int d=0;d<8;d++){
            y[d] = fe*sacc[d];
            y2p = fmaf(y[d],y[d],y2p);
            cydp = fmaf(c[d],y[d],cydp);
        }
        const float y2 = red16(y2p);
        const float cyd = red16(cydp);
        const float n1 = 1.f + 2.f*cyd + y2;
        const float n2 = 1.f - cur2;
        const float rdn = __fdividef(1.f, fmaxf(1.f + 2.f*cyd + cur2*y2, MINF));
        float nv[8], pn2p=0.f;
        #pragma unroll
        for (int d=0;d<8;d++){
            nv[d] = (n1*c[d] + n2*y[d])*rdn;
            pn2p = fmaf(nv[d],nv[d],pn2p);
        }
        const float pn2 = red16(pn2p);
        const float pn = fmaxf(sqrtf(pn2), MINF);
        const float sc = (pn > BALLMAX) ? __fdividef(BALLMAX, pn) : 1.f;
        #pragma unroll
        for (int d=0;d<8;d++) c[d] = nv[d]*sc;
    }
    float* st = out4 + (size_t)b*1792 + i*128 + s*8;
    const float4 o0 = {c[0],c[1],c[2],c[3]}, o1 = {c[4],c[5],c[6],c[7]};
    *(float4*)st = o0; *(float4*)(st+4) = o1;
}

// Kernel 4: softmax-weighted Mobius fusion + projx + broadcast to [B,14,128].
__global__ __launch_bounds__(256) void k_fuse(const float* __restrict__ fw, float* __restrict__ out4)
{
    const int b    = (blockIdx.x<<2) + (threadIdx.x>>6);
    const int lane = threadIdx.x & 63;
    float* slice = out4 + (size_t)b*1792;
    float2 p[4];
    #pragma unroll
    for (int i=0;i<4;i++) p[i] = *(const float2*)(slice + i*128 + lane*2);
    const float f0=fw[0], f1=fw[1], f2=fw[2], f3=fw[3];
    const float mx = fmaxf(fmaxf(f0,f1), fmaxf(f2,f3));
    const float e0=expf(f0-mx), e1=expf(f1-mx), e2=expf(f2-mx), e3=expf(f3-mx);
    const float iz = 1.f/(e0+e1+e2+e3);
    const float ww[4] = {e0*iz, e1*iz, e2*iz, e3*iz};
    float cx, cy;
    {
        const float n2 = wred64(p[0].x*p[0].x + p[0].y*p[0].y);
        const float n = fmaxf(sqrtf(n2), MINF);
        const float f = __fdividef(ftanh(ww[0]*fatanh(fminf(n, ATMAX))), n);
        cx = f*p[0].x; cy = f*p[0].y;
    }
    #pragma unroll
    for (int i=1;i<4;i++){
        const float n2 = wred64(p[i].x*p[i].x + p[i].y*p[i].y);
        const float n = fmaxf(sqrtf(n2), MINF);
        const float f = __fdividef(ftanh(ww[i]*fatanh(fminf(n, ATMAX))), n);
        const float txv = f*p[i].x, tyv = f*p[i].y;
        const float c2 = wred64(cx*cx+cy*cy);
        const float t2 = wred64(txv*txv+tyv*tyv);
        const float ct = wred64(cx*txv+cy*tyv);
        const float n1 = 1.f+2.f*ct+t2, nk = 1.f-c2;
        const float dn = fmaxf(1.f+2.f*ct+c2*t2, MINF);
        const float rdn = __fdividef(1.f, dn);
        cx = (n1*cx+nk*txv)*rdn; cy = (n1*cy+nk*tyv)*rdn;
    }
    {
        const float n2 = wred64(cx*cx+cy*cy);
        const float n = fmaxf(sqrtf(n2), MINF);
        if (n > BALLMAX){ const float sc=__fdividef(BALLMAX,n); cx*=sc; cy*=sc; }
    }
    const float2 o = make_float2(cx,cy);
    #pragma unroll
    for (int nseg=0; nseg<14; ++nseg)
        *(float2*)(slice + nseg*128 + lane*2) = o;
}

extern "C" void kernel_launch(void* const* d_in, const int* in_sizes, int n_in,
                              void* d_out, int out_size, void* d_ws, size_t ws_size,
                              hipStream_t stream)
{
    const float* x0 = (const float*)d_in[0];
    const float* x1 = (const float*)d_in[1];
    const float* x2 = (const float*)d_in[2];
    const float* x3 = (const float*)d_in[3];
    const float* W1 = (const float*)d_in[4];
    const float* b1 = (const float*)d_in[5];
    const float* lg = (const float*)d_in[6];
    const float* lb = (const float*)d_in[7];
    const float* W2 = (const float*)d_in[8];
    const float* b2 = (const float*)d_in[9];
    const float* es = (const float*)d_in[10];
    const float* fw = (const float*)d_in[11];
    float* out  = (float*)d_out;
    float* out4 = out + (size_t)4*14336*128;
    float* ws   = (float*)d_ws;

    dim3 gp(56, 4);
    k_prep<<<gp, 256, 0, stream>>>(W1, ws);
    dim3 g1(112, 4);
    k_enc1<<<g1, 256, 0, stream>>>(x0,x1,x2,x3,ws,b1,lg,lb,out);
    k_enc2<<<1792, 256, 0, stream>>>(W2,b2,es,out);
    k_pool<<<256, 256, 0, stream>>>(out,out4);
    k_fuse<<<256, 256, 0, stream>>>(fw,out4);
}